// Round 1
// 101.554 us; speedup vs baseline: 1.0291x; 1.0291x over previous
//
#include <hip/hip_runtime.h>
#include <math.h>

#define NF 39
#define CONT_F 13
#define CATE_F 26
#define EMB_D 40
#define VOCAB 100000
#define NCH 9          // 8 attn channels + 1 fc channel
#define ROW_B 80       // LDS row stride bytes: 40 bf16 = 80 B
#define CH_B  3120     // bytes per channel: 39 rows * 80 B
#define BLK_T 192
#define GRID_MAX 1024  // 4 blocks/CU * 256 CU -> fully resident, 4 rows/block

typedef __attribute__((ext_vector_type(8))) short short8;   // 8 bf16 (4 VGPRs)
typedef __attribute__((ext_vector_type(4))) float f32x4;    // 4 fp32 acc

// Truncating fp32->bf16 pack of two values in ONE v_perm_b32.
// D = {b.byte3, b.byte2, a.byte3, a.byte2} == (bits(b)&0xFFFF0000)|(bits(a)>>16)
// Bit-identical to the previous 3-op shift/and/or pack.
__device__ __forceinline__ unsigned pk2(float a, float b) {
    return __builtin_amdgcn_perm(__float_as_uint(b), __float_as_uint(a), 0x07060302u);
}

__global__ __launch_bounds__(BLK_T, 3)
void afm_mfma_kernel(const float* __restrict__ conts,   // (B,13)
                     const int*   __restrict__ cates,   // (B,26)
                     const float* __restrict__ emb,     // (100000,40)
                     const float* __restrict__ attn_W,  // (8,40)
                     const float* __restrict__ attn_b,  // (8,)
                     const float* __restrict__ proj_W,  // (1,8)
                     const float* __restrict__ fc_W,    // (1,40)
                     const float* __restrict__ fc_b,    // (1,)
                     float* __restrict__ out,           // (B,1)
                     int batch)
{
    __shared__ __attribute__((aligned(16))) unsigned short Xb[NF * EMB_D];
    __shared__ __attribute__((aligned(16))) unsigned short Aall[NCH * NF * EMB_D];
    __shared__ __attribute__((aligned(16))) float Wlds[NCH * 10 * 4]; // 90 float4
    __shared__ __attribute__((aligned(16))) float zero16[4];          // K-pad target
    __shared__ float reds[3], redg[3];

    const int tid = threadIdx.x;
    const float4* emb4 = (const float4*)emb;

    // -------- one-time LDS init (visible after first barrier) --------
    if (tid < 4) zero16[tid] = 0.f;
    if (tid < NCH * 10) {
        const int c = tid / 10, q = tid % 10;
        ((float4*)Wlds)[tid] = (c < 8) ? ((const float4*)attn_W)[c * 10 + q]
                                       : ((const float4*)fc_W)[q];
    }

    // -------- per-thread staging geometry (loop-invariant) --------
    // items t = tid, tid+192, tid+384(<6). Item0 is a cont field iff t<130;
    // items 1,2 are always cate fields (t>=192 -> f>=19).
    int f_[3], q_[3], wofs[3];
    #pragma unroll
    for (int k = 0; k < 3; ++k) {
        const int t = tid + k * BLK_T;
        const int f = t / 10;
        f_[k] = f; q_[k] = t - f * 10;
        wofs[k] = f * 20 + q_[k] * 2;       // 32-bit words within a channel
    }
    const bool act2  = (tid < 6);
    const bool cont0 = (tid < 130);

    const int stride = gridDim.x;
    int r = blockIdx.x;

    // pipeline registers
    float  csI0;  int uI[3];       // indices for row r+stride
    float4 vaG[3]; float csG0;     // gathered embedding data (next row)

    auto idx_load = [&](int rowi) {
        if (cont0) { csI0 = conts[rowi * CONT_F + f_[0]]; }
        else {
            unsigned u = (unsigned)cates[rowi * CATE_F + (f_[0] - CONT_F)];
            uI[0] = (u >= (unsigned)VOCAB) ? 0 : (int)u;
        }
        {
            unsigned u = (unsigned)cates[rowi * CATE_F + (f_[1] - CONT_F)];
            uI[1] = (u >= (unsigned)VOCAB) ? 0 : (int)u;
        }
        if (act2) {
            unsigned u = (unsigned)cates[rowi * CATE_F + (f_[2] - CONT_F)];
            uI[2] = (u >= (unsigned)VOCAB) ? 0 : (int)u;
        }
    };
    auto gather = [&]() {
        const int er0 = cont0 ? f_[0] : uI[0];
        vaG[0] = emb4[er0 * 10 + q_[0]];
        csG0   = cont0 ? csI0 : 1.f;
        vaG[1] = emb4[uI[1] * 10 + q_[1]];
        if (act2) vaG[2] = emb4[uI[2] * 10 + q_[2]];
    };
    auto pack_item = [&](float4 v, float cs, int wofsk, int qk) {
        v.x *= cs; v.y *= cs; v.z *= cs; v.w *= cs;
        unsigned* XbW = (unsigned*)Xb;
        unsigned* AW  = (unsigned*)Aall;
        *(uint2*)&XbW[wofsk] = make_uint2(pk2(v.x, v.y), pk2(v.z, v.w));
        #pragma unroll
        for (int c = 0; c < NCH; ++c) {
            const float4 wv = ((const float4*)Wlds)[c * 10 + qk];
            *(uint2*)&AW[c * 780 + wofsk] =
                make_uint2(pk2(v.x * wv.x, v.y * wv.y), pk2(v.z * wv.z, v.w * wv.w));
        }
    };
    auto pack_write = [&]() {
        pack_item(vaG[0], csG0, wofs[0], q_[0]);
        pack_item(vaG[1], 1.f,  wofs[1], q_[1]);
        if (act2) pack_item(vaG[2], 1.f, wofs[2], q_[2]);
    };

    // -------- compute-phase invariants --------
    const int wid  = tid >> 6;       // = stripe m, 0..2
    const int lane = tid & 63;
    const int l15  = lane & 15;
    const int quad = lane >> 4;
    int rA = wid * 16 + l15; if (rA > NF - 1) rA = NF - 1;

    const char* XbP = (const char*)Xb;
    const char* AP  = (const char*)Aall;
    const char* ZP  = (const char*)zero16;

    float pj[8], bb[8];
    #pragma unroll
    for (int a = 0; a < 8; ++a) { pj[a] = proj_W[a]; bb[a] = attn_b[a]; }
    const float fcb = fc_b[0];

    // -------- prologue: stage row r (exposed latency paid once) --------
    idx_load(r);
    gather();
    { int rn = r + stride; idx_load(rn < batch ? rn : 0); }
    __syncthreads();        // Wlds/zero16 ready
    pack_write();
    __syncthreads();        // row r staged in LDS

    // -------- pipelined row loop --------
    for (;;) {
        const int rn = r + stride;
        const bool hn = (rn < batch);

        // issue next row's gathers NOW (latency hides under this row's compute)
        if (hn) gather();
        { int r2 = rn + stride; idx_load(r2 < batch ? r2 : 0); }

        // ---- compute row r: 9-channel Gram, m-stripe per wave ----
        short8 b0[3], b1[3];
        #pragma unroll
        for (int nt = 0; nt < 3; ++nt) {
            if (nt >= wid) {
                int rB = nt * 16 + l15; if (rB > NF - 1) rB = NF - 1;
                b0[nt] = *(const short8*)(XbP + rB * ROW_B + quad * 16);
                b1[nt] = *(const short8*)((quad == 0) ? (XbP + rB * ROW_B + 64) : ZP);
            }
        }

        float lacc[3][4] = {{0.f}};
        float gv[3][4];
        #pragma unroll
        for (int c = 0; c < NCH; ++c) {
            const char* aRow = AP + c * CH_B + rA * ROW_B;
            const short8 a0 = *(const short8*)(aRow + quad * 16);
            const short8 a1 = *(const short8*)((quad == 0) ? (aRow + 64) : ZP);
            #pragma unroll
            for (int nt = 0; nt < 3; ++nt) {
                if (nt >= wid) {
                    f32x4 t = {0.f, 0.f, 0.f, 0.f};
                    t = __builtin_amdgcn_mfma_f32_16x16x32_bf16(a0, b0[nt], t, 0, 0, 0);
                    t = __builtin_amdgcn_mfma_f32_16x16x32_bf16(a1, b1[nt], t, 0, 0, 0);
                    #pragma unroll
                    for (int rr = 0; rr < 4; ++rr) {
                        if (c < 8)
                            lacc[nt][rr] = fmaf(pj[c], fmaxf(t[rr] + bb[c], 0.f),
                                                lacc[nt][rr]);
                        else
                            gv[nt][rr] = t[rr];
                    }
                }
            }
        }

        // ---- max-free softmax partials (|logit| ~ 1e-8 analytically) ----
        float s = 0.f, gs = 0.f;
        #pragma unroll
        for (int nt = 0; nt < 3; ++nt) {
            if (nt >= wid) {
                #pragma unroll
                for (int rr = 0; rr < 4; ++rr) {
                    const int i = wid * 16 + quad * 4 + rr;
                    const int j = nt * 16 + l15;
                    if (i < j && j < NF) {
                        const float e = __expf(lacc[nt][rr]);
                        s += e;
                        gs = fmaf(e, gv[nt][rr], gs);
                    }
                }
            }
        }
        #pragma unroll
        for (int off = 32; off; off >>= 1) {
            s  += __shfl_xor(s, off);
            gs += __shfl_xor(gs, off);
        }
        if (lane == 0) { reds[wid] = s; redg[wid] = gs; }
        __syncthreads();     // compute's LDS reads done; gathers drained here too

        if (tid == 0) {
            const float S = reds[0] + reds[1] + reds[2];
            const float G = redg[0] + redg[1] + redg[2];
            const float zf = G / S + fcb;
            out[r] = 1.f / (1.f + __expf(-zf));
        }

        // stage next row into LDS behind everyone's reads
        if (hn) pack_write();
        __syncthreads();

        if (!hn) break;
        r = rn;
    }
}

extern "C" void kernel_launch(void* const* d_in, const int* in_sizes, int n_in,
                              void* d_out, int out_size, void* d_ws, size_t ws_size,
                              hipStream_t stream) {
    const float* conts  = (const float*)d_in[0];
    const int*   cates  = (const int*)  d_in[1];
    // d_in[2] = combs: unused by the reference computation
    const float* emb    = (const float*)d_in[3];
    const float* attn_W = (const float*)d_in[4];
    const float* attn_b = (const float*)d_in[5];
    const float* proj_W = (const float*)d_in[6];
    const float* fc_W   = (const float*)d_in[7];
    const float* fc_b   = (const float*)d_in[8];
    float* out = (float*)d_out;

    const int batch = in_sizes[0] / CONT_F;  // 4096
    int grid = batch < GRID_MAX ? batch : GRID_MAX;
    afm_mfma_kernel<<<grid, BLK_T, 0, stream>>>(
        conts, cates, emb, attn_W, attn_b, proj_W, fc_W, fc_b, out, batch);
}

// Round 2
// 91.561 us; speedup vs baseline: 1.1414x; 1.1091x over previous
//
#include <hip/hip_runtime.h>
#include <math.h>

#define NF 39
#define CONT_F 13
#define CATE_F 26
#define EMB_D 40
#define VOCAB 100000
#define NCH 9          // 8 attn channels + 1 fc channel

typedef __attribute__((ext_vector_type(8))) short short8;   // 8 bf16 (4 VGPRs)
typedef __attribute__((ext_vector_type(4))) float f32x4;    // 4 fp32 acc

union frag { short8 s; uint4 u; };

// Truncating fp32->bf16 pack of two values in ONE v_perm_b32.
// D = (bits(b)&0xFFFF0000) | (bits(a)>>16); a -> low bf16 (element 0).
__device__ __forceinline__ unsigned pk2(float a, float b) {
    return __builtin_amdgcn_perm(__float_as_uint(b), __float_as_uint(a), 0x07060302u);
}

// One row per WAVE. No __syncthreads after init; no X/A staging in LDS.
// Gram fragments: for 16x16x32 bf16 MFMA, A-frag and B-frag use the SAME
// per-lane slice X[16m+l15][quad*8..+7]  (verified by the previous kernel,
// which read a0/b0 with identical addressing). So the wave holds X once and
// derives per-channel A = bf16(x_f32 * W_c) on the fly.
// K layout: MFMA#1 k=d0..31. MFMA#2 (tail): slot quad*8+{0,1} <- d=32+2q,33+2q;
// slot 2 (quad0) carries the attn bias column: A=bb_c, B=1.0.
__global__ __launch_bounds__(256, 2)
void afm_wave_kernel(const float* __restrict__ conts,   // (B,13)
                     const int*   __restrict__ cates,   // (B,26)
                     const float* __restrict__ emb,     // (100000,40)
                     const float* __restrict__ attn_W,  // (8,40)
                     const float* __restrict__ attn_b,  // (8,)
                     const float* __restrict__ proj_W,  // (1,8)
                     const float* __restrict__ fc_W,    // (1,40)
                     const float* __restrict__ fc_b,    // (1,)
                     float* __restrict__ out,           // (B,1)
                     int batch)
{
    __shared__ __attribute__((aligned(16))) float Wlds[NCH * EMB_D]; // 1440 B

    const int tid = threadIdx.x;
    if (tid < NCH * 10) {
        const int c = tid / 10, q = tid % 10;
        ((float4*)Wlds)[tid] = (c < 8) ? ((const float4*)attn_W)[c * 10 + q]
                                       : ((const float4*)fc_W)[q];
    }

    // uniform scalars (compiler scalarizes these uniform loads)
    float pj[8], bb[8];
    #pragma unroll
    for (int a = 0; a < 8; ++a) { pj[a] = proj_W[a]; bb[a] = attn_b[a]; }
    const float fcb = fc_b[0];

    __syncthreads();   // Wlds ready; the ONLY barrier.

    const int wave = tid >> 6;
    const int lane = tid & 63;
    const int l15  = lane & 15;
    const int quad = lane >> 4;
    const int row  = blockIdx.x * 4 + wave;
    if (row >= batch) return;

    // ---------------- index loads (3 fields per lane) ----------------
    int erow[3];
    float cs = 1.f;
    const bool contl = (l15 < CONT_F);
    if (contl) {
        erow[0] = l15;
        cs = conts[row * CONT_F + l15];
    } else {
        unsigned u = (unsigned)cates[row * CATE_F + (l15 - CONT_F)];
        erow[0] = (u >= (unsigned)VOCAB) ? 0 : (int)u;
    }
    {
        unsigned u = (unsigned)cates[row * CATE_F + (3 + l15)];       // field 16+l15
        erow[1] = (u >= (unsigned)VOCAB) ? 0 : (int)u;
    }
    {
        int f2 = 32 + l15; if (f2 > NF - 1) f2 = NF - 1;              // dup field 38
        unsigned u = (unsigned)cates[row * CATE_F + (f2 - CONT_F)];
        erow[2] = (u >= (unsigned)VOCAB) ? 0 : (int)u;
    }

    // ---------------- gather X slices (f32) ----------------
    float xf[3][8];      // d = quad*8 .. quad*8+7
    float xe[3][2];      // d = 32+quad*2, 33+quad*2
    #pragma unroll
    for (int m = 0; m < 3; ++m) {
        const char* rp = (const char*)emb + (size_t)erow[m] * 160;
        const float4 h0 = *(const float4*)(rp + quad * 32);
        const float4 h1 = *(const float4*)(rp + quad * 32 + 16);
        const float2 t0 = *(const float2*)(rp + 128 + quad * 8);
        xf[m][0] = h0.x; xf[m][1] = h0.y; xf[m][2] = h0.z; xf[m][3] = h0.w;
        xf[m][4] = h1.x; xf[m][5] = h1.y; xf[m][6] = h1.z; xf[m][7] = h1.w;
        xe[m][0] = t0.x; xe[m][1] = t0.y;
    }
    if (contl) {   // stripe 0 rows 0..12 are cont fields: scale by value
        #pragma unroll
        for (int t = 0; t < 8; ++t) xf[0][t] *= cs;
        xe[0][0] *= cs; xe[0][1] *= cs;
    }

    // ---------------- pack B-side (= unscaled X) fragments ----------------
    frag xb[3], xb2[3];
    const unsigned onew = (quad == 0) ? pk2(1.0f, 0.0f) : 0u;  // bias column B=1
    #pragma unroll
    for (int m = 0; m < 3; ++m) {
        xb[m].u = make_uint4(pk2(xf[m][0], xf[m][1]), pk2(xf[m][2], xf[m][3]),
                             pk2(xf[m][4], xf[m][5]), pk2(xf[m][6], xf[m][7]));
        xb2[m].u = make_uint4(pk2(xe[m][0], xe[m][1]), onew, 0u, 0u);
    }

    // ---------------- 9-channel Gram, all 6 upper tiles in-wave ----------------
    static const int TM[6] = {0, 0, 0, 1, 1, 2};
    static const int TN[6] = {0, 1, 2, 1, 2, 2};
    float lacc[6][4] = {{0.f}};
    float gv[6][4];

    #pragma unroll
    for (int c = 0; c < NCH; ++c) {
        const float* wrow = Wlds + c * EMB_D;
        const float4 w0 = *(const float4*)(wrow + quad * 8);
        const float4 w1 = *(const float4*)(wrow + quad * 8 + 4);
        const float2 wt = *(const float2*)(wrow + 32 + quad * 2);
        // a-side bias column (k slot 2, quad0): A[i][slot]=bb_c for all i
        const unsigned bw = (quad == 0 && c < 8) ? pk2(bb[c], 0.0f) : 0u;

        frag a0[3], a1[3];
        #pragma unroll
        for (int m = 0; m < 3; ++m) {
            a0[m].u = make_uint4(pk2(xf[m][0] * w0.x, xf[m][1] * w0.y),
                                 pk2(xf[m][2] * w0.z, xf[m][3] * w0.w),
                                 pk2(xf[m][4] * w1.x, xf[m][5] * w1.y),
                                 pk2(xf[m][6] * w1.z, xf[m][7] * w1.w));
            a1[m].u = make_uint4(pk2(xe[m][0] * wt.x, xe[m][1] * wt.y), bw, 0u, 0u);
        }

        #pragma unroll
        for (int tt = 0; tt < 6; ++tt) {
            f32x4 t = {0.f, 0.f, 0.f, 0.f};
            t = __builtin_amdgcn_mfma_f32_16x16x32_bf16(a0[TM[tt]].s, xb[TN[tt]].s, t, 0, 0, 0);
            t = __builtin_amdgcn_mfma_f32_16x16x32_bf16(a1[TM[tt]].s, xb2[TN[tt]].s, t, 0, 0, 0);
            if (c < 8) {
                #pragma unroll
                for (int rr = 0; rr < 4; ++rr)   // bias already in t via MFMA
                    lacc[tt][rr] = fmaf(pj[c], fmaxf(t[rr], 0.f), lacc[tt][rr]);
            } else {
                #pragma unroll
                for (int rr = 0; rr < 4; ++rr) gv[tt][rr] = t[rr];
            }
        }
    }

    // ---------------- max-free softmax + output (wave-local) ----------------
    // |logit| <= ~1e-8 analytically (emb scale (3/1040)^2): exp w/o max-sub.
    float s = 0.f, gs = 0.f;
    #pragma unroll
    for (int tt = 0; tt < 6; ++tt) {
        #pragma unroll
        for (int rr = 0; rr < 4; ++rr) {
            const int i = TM[tt] * 16 + quad * 4 + rr;
            const int j = TN[tt] * 16 + l15;
            if (i < j && j < NF) {
                const float e = __expf(lacc[tt][rr]);
                s += e;
                gs = fmaf(e, gv[tt][rr], gs);
            }
        }
    }
    #pragma unroll
    for (int off = 32; off; off >>= 1) {
        s  += __shfl_xor(s, off);
        gs += __shfl_xor(gs, off);
    }
    if (lane == 0) {
        const float zf = gs / s + fcb;
        out[row] = 1.f / (1.f + __expf(-zf));
    }
}

extern "C" void kernel_launch(void* const* d_in, const int* in_sizes, int n_in,
                              void* d_out, int out_size, void* d_ws, size_t ws_size,
                              hipStream_t stream) {
    const float* conts  = (const float*)d_in[0];
    const int*   cates  = (const int*)  d_in[1];
    // d_in[2] = combs: unused by the reference computation
    const float* emb    = (const float*)d_in[3];
    const float* attn_W = (const float*)d_in[4];
    const float* attn_b = (const float*)d_in[5];
    const float* proj_W = (const float*)d_in[6];
    const float* fc_W   = (const float*)d_in[7];
    const float* fc_b   = (const float*)d_in[8];
    float* out = (float*)d_out;

    const int batch = in_sizes[0] / CONT_F;  // 4096
    const int grid = (batch + 3) / 4;        // 1 row per wave, 4 waves per block
    afm_wave_kernel<<<grid, 256, 0, stream>>>(
        conts, cates, emb, attn_W, attn_b, proj_W, fc_W, fc_b, out, batch);
}